// Round 3
// baseline (141.968 us; speedup 1.0000x reference)
//
#include <hip/hip_runtime.h>

// Reference collapses: attention branch == 1.0 exactly (softmax over size-1
// axis -> ones; attn rows sum to 1). Survivor:
//   out[b, o*576 + p] = 1 + gelu( conv3x3(x4, local_w, groups=2, pad=1)*s[o] + t[o] )
// s[o] = bnc1_gamma[o]*rsqrt(1+eps), t[o] = bnc1_beta[o]; flat NCHW order.
//
// R2 structure: one block per (b,o). 576 threads = 72 spatial units (24 rows
// x 3 col-octets) x 8 channel-slices (8 input channels each). Per conv row a
// unit loads halo-scalar + 2 aligned float4 + halo-scalar (4 VMEM for 24
// FMAs) -> 72 global loads/lane vs 567 in R1. Weights staged in LDS (channel
// index is lane-dependent -> no scalar-load uniformity). Invalid conv rows
// neutralized by zeroing the 3 row-weights; col halos clamped+zeroed once.
// 8 partial sums reduced through LDS; epilogue = BN + exact gelu + 1.

__global__ __launch_bounds__(576, 1) void fused_conv_gelu(
    const float* __restrict__ x,    // (2,128,24,24) flat
    const float* __restrict__ lw,   // (128,64,3,3) flat
    const float* __restrict__ gam,  // (128,)
    const float* __restrict__ bet,  // (128,)
    float* __restrict__ out)        // (2,576,128) flat == (2,128,24,24) flat
{
    __shared__ float wlds[576];
    __shared__ float part[8][576];

    const int bi = blockIdx.x;      // 0..255
    const int b  = bi >> 7;
    const int o  = bi & 127;
    const int g  = o >> 6;
    const int t  = threadIdx.x;     // 0..575

    // stage this output channel's 64x3x3 weights in LDS (one load/thread)
    wlds[t] = lw[o * 576 + t];
    __syncthreads();

    const int s  = t / 72;          // channel slice: channels 8s .. 8s+7
    const int u  = t % 72;          // spatial unit
    const int r  = u / 3;           // output row 0..23
    const int w0 = (u % 3) * 8;     // output col base in {0,8,16}

    const float* __restrict__ xp = x + (b * 128 + g * 64) * 576;

    // row info (channel-invariant): clamped row index + validity
    int  rrc[3];
    bool rv[3];
#pragma unroll
    for (int dr = 0; dr < 3; ++dr) {
        const int rr = r + dr - 1;
        rv[dr]  = (rr >= 0) && (rr < 24);
        rrc[dr] = min(max(rr, 0), 23);
    }
    // col halos (clamped address; invalid -> value zeroed)
    const bool lval = (w0 != 0);
    const bool rval = (w0 != 16);
    const int  wl   = lval ? (w0 - 1) : 0;
    const int  wr   = rval ? (w0 + 8) : 23;

    float acc[8];
#pragma unroll
    for (int j = 0; j < 8; ++j) acc[j] = 0.0f;

#pragma unroll
    for (int ic = 0; ic < 8; ++ic) {
        const int i = s * 8 + ic;                 // input channel within group
        const float* __restrict__ cp = xp + i * 576;
        const float* __restrict__ wc = &wlds[i * 9];

#pragma unroll
        for (int dr = 0; dr < 3; ++dr) {
            const float* __restrict__ rp = cp + rrc[dr] * 24;
            // window W[k] == input col (w0-1+k), k=0..9; all addrs in-bounds,
            // quads 16B-aligned (576,24,w0 all multiples of 4 elements/16B).
            float W[10];
            W[0] = lval ? rp[wl] : 0.0f;
            const float4 q1 = *(const float4*)(rp + w0);
            const float4 q2 = *(const float4*)(rp + w0 + 4);
            W[1] = q1.x; W[2] = q1.y; W[3] = q1.z; W[4] = q1.w;
            W[5] = q2.x; W[6] = q2.y; W[7] = q2.z; W[8] = q2.w;
            W[9] = rval ? rp[wr] : 0.0f;
            // invalid conv row -> zero the row's weights (kills all its taps)
            const float wg0 = rv[dr] ? wc[dr * 3 + 0] : 0.0f;
            const float wg1 = rv[dr] ? wc[dr * 3 + 1] : 0.0f;
            const float wg2 = rv[dr] ? wc[dr * 3 + 2] : 0.0f;
#pragma unroll
            for (int j = 0; j < 8; ++j)
                acc[j] = fmaf(wg0, W[j],
                         fmaf(wg1, W[j + 1],
                         fmaf(wg2, W[j + 2], acc[j])));
        }
    }

    // write this slice's 8 contiguous partials (16B-aligned LDS stores)
    {
        float4 a0, a1;
        a0.x = acc[0]; a0.y = acc[1]; a0.z = acc[2]; a0.w = acc[3];
        a1.x = acc[4]; a1.y = acc[5]; a1.z = acc[6]; a1.w = acc[7];
        float* pp = &part[s][r * 24 + w0];
        *(float4*)(pp)     = a0;
        *(float4*)(pp + 4) = a1;
    }
    __syncthreads();

    // reduce 8 slices for pixel p = t (stride-576 reads: 2 lanes/bank, free)
    float v = 0.0f;
#pragma unroll
    for (int ss = 0; ss < 8; ++ss) v += part[ss][t];

    const float scale = gam[o] * rsqrtf(1.0f + 1e-5f);
    const float shift = bet[o];
    const float y  = fmaf(v, scale, shift);
    const float gl = 0.5f * y * (1.0f + erff(y * 0.70710678118654752f));
    out[b * 73728 + o * 576 + t] = 1.0f + gl;
}

extern "C" void kernel_launch(void* const* d_in, const int* in_sizes, int n_in,
                              void* d_out, int out_size, void* d_ws, size_t ws_size,
                              hipStream_t stream) {
    const float* x   = (const float*)d_in[0];   // x
    const float* lw  = (const float*)d_in[9];   // local_w
    const float* gam = (const float*)d_in[10];  // bnc1_gamma
    const float* bet = (const float*)d_in[11];  // bnc1_beta
    float* out = (float*)d_out;

    fused_conv_gelu<<<dim3(256), dim3(576), 0, stream>>>(x, lw, gam, bet, out);
}

// Round 4
// 87.525 us; speedup vs baseline: 1.6220x; 1.6220x over previous
//
#include <hip/hip_runtime.h>

// Reference collapses: attention branch == 1.0 exactly (softmax over size-1
// axis -> ones; attn rows sum to 1). Survivor:
//   out[b, o*576 + p] = 1 + gelu( conv3x3(x4, local_w, groups=2, pad=1)*s[o] + t[o] )
// s[o] = bnc1_gamma[o]*rsqrt(1+eps), t[o] = bnc1_beta[o]; flat NCHW order.
//
// R4: R2's structure (one block per (b,o); 576 threads = 72 spatial units
// [24 rows x 3 col-octets] x 8 channel-slices; 4 VMEM per 24 FMAs; weights
// in LDS; 8-slice LDS reduction) but with the register-pressure bug fixed:
// R3 fully unrolled 8x3 iterations -> 96 hoisted loads + W[10] array blew
// the 84-VGPR (6 waves/EU) budget -> ~140 MB of scratch spill traffic
// (observed WRITE_SIZE=134MB). Here the channel loop is NOT unrolled
// (#pragma unroll 1) and the float4s feed the FMA tree directly; live set
// ~35 VGPRs, no spills.

__global__ __launch_bounds__(576, 1) void fused_conv_gelu(
    const float* __restrict__ x,    // (2,128,24,24) flat
    const float* __restrict__ lw,   // (128,64,3,3) flat
    const float* __restrict__ gam,  // (128,)
    const float* __restrict__ bet,  // (128,)
    float* __restrict__ out)        // (2,576,128) flat == (2,128,24,24) flat
{
    __shared__ float wlds[576];
    __shared__ float part[8][576];

    const int bi = blockIdx.x;      // 0..255
    const int b  = bi >> 7;
    const int o  = bi & 127;
    const int g  = o >> 6;
    const int t  = threadIdx.x;     // 0..575

    // stage this output channel's 64x3x3 weights in LDS (one load/thread)
    wlds[t] = lw[o * 576 + t];
    __syncthreads();

    const int s  = t / 72;          // channel slice: channels 8s .. 8s+7
    const int u  = t % 72;          // spatial unit
    const int r  = u / 3;           // output row 0..23
    const int w0 = (u % 3) * 8;     // output col base in {0,8,16}

    const float* __restrict__ xp = x + (b * 128 + g * 64) * 576;

    // row info (channel-invariant): clamped row index + validity
    int  rrc[3];
    bool rv[3];
#pragma unroll
    for (int dr = 0; dr < 3; ++dr) {
        const int rr = r + dr - 1;
        rv[dr]  = (rr >= 0) && (rr < 24);
        rrc[dr] = min(max(rr, 0), 23);
    }
    // col halos (clamped address; invalid -> value zeroed)
    const bool lval = (w0 != 0);
    const bool rval = (w0 != 16);
    const int  wl   = lval ? (w0 - 1) : 0;
    const int  wr   = rval ? (w0 + 8) : 23;

    float acc[8];
#pragma unroll
    for (int j = 0; j < 8; ++j) acc[j] = 0.0f;

#pragma unroll 1
    for (int ic = 0; ic < 8; ++ic) {
        const int i = s * 8 + ic;                 // input channel within group
        const float* __restrict__ cp = xp + i * 576;
        const float* __restrict__ wc = &wlds[i * 9];

#pragma unroll
        for (int dr = 0; dr < 3; ++dr) {
            const float* __restrict__ rp = cp + rrc[dr] * 24;
            // cols: hl = w0-1, q1 = w0..w0+3, q2 = w0+4..w0+7, hr = w0+8.
            // All addresses in-bounds (halos clamped), quads 16B-aligned.
            const float  hl = lval ? rp[wl] : 0.0f;
            const float4 q1 = *(const float4*)(rp + w0);
            const float4 q2 = *(const float4*)(rp + w0 + 4);
            const float  hr = rval ? rp[wr] : 0.0f;
            // invalid conv row -> zero the row's weights (kills all its taps)
            const float wg0 = rv[dr] ? wc[dr * 3 + 0] : 0.0f;
            const float wg1 = rv[dr] ? wc[dr * 3 + 1] : 0.0f;
            const float wg2 = rv[dr] ? wc[dr * 3 + 2] : 0.0f;

            acc[0] = fmaf(wg0, hl,   fmaf(wg1, q1.x, fmaf(wg2, q1.y, acc[0])));
            acc[1] = fmaf(wg0, q1.x, fmaf(wg1, q1.y, fmaf(wg2, q1.z, acc[1])));
            acc[2] = fmaf(wg0, q1.y, fmaf(wg1, q1.z, fmaf(wg2, q1.w, acc[2])));
            acc[3] = fmaf(wg0, q1.z, fmaf(wg1, q1.w, fmaf(wg2, q2.x, acc[3])));
            acc[4] = fmaf(wg0, q1.w, fmaf(wg1, q2.x, fmaf(wg2, q2.y, acc[4])));
            acc[5] = fmaf(wg0, q2.x, fmaf(wg1, q2.y, fmaf(wg2, q2.z, acc[5])));
            acc[6] = fmaf(wg0, q2.y, fmaf(wg1, q2.z, fmaf(wg2, q2.w, acc[6])));
            acc[7] = fmaf(wg0, q2.z, fmaf(wg1, q2.w, fmaf(wg2, hr,   acc[7])));
        }
    }

    // write this slice's 8 contiguous partials (16B-aligned LDS stores)
    {
        float4 a0, a1;
        a0.x = acc[0]; a0.y = acc[1]; a0.z = acc[2]; a0.w = acc[3];
        a1.x = acc[4]; a1.y = acc[5]; a1.z = acc[6]; a1.w = acc[7];
        float* pp = &part[s][r * 24 + w0];
        *(float4*)(pp)     = a0;
        *(float4*)(pp + 4) = a1;
    }
    __syncthreads();

    // reduce 8 slices for pixel p = t (stride-576 reads: conflict-free)
    float v = 0.0f;
#pragma unroll
    for (int ss = 0; ss < 8; ++ss) v += part[ss][t];

    const float scale = gam[o] * rsqrtf(1.0f + 1e-5f);
    const float shift = bet[o];
    const float y  = fmaf(v, scale, shift);
    const float gl = 0.5f * y * (1.0f + erff(y * 0.70710678118654752f));
    out[b * 73728 + o * 576 + t] = 1.0f + gl;
}

extern "C" void kernel_launch(void* const* d_in, const int* in_sizes, int n_in,
                              void* d_out, int out_size, void* d_ws, size_t ws_size,
                              hipStream_t stream) {
    const float* x   = (const float*)d_in[0];   // x
    const float* lw  = (const float*)d_in[9];   // local_w
    const float* gam = (const float*)d_in[10];  // bnc1_gamma
    const float* bet = (const float*)d_in[11];  // bnc1_beta
    float* out = (float*)d_out;

    fused_conv_gelu<<<dim3(256), dim3(576), 0, stream>>>(x, lw, gam, bet, out);
}